// Round 1
// 160.219 us; speedup vs baseline: 1.0163x; 1.0163x over previous
//
#include <hip/hip_runtime.h>
#include <hip/hip_bf16.h>
#include <math.h>

#define HSZ   1024
#define NHEAD 16
#define HDIM  64
#define BATCH 2
#define SEQ   2048

#define LOG2E 1.4426950408889634f

typedef __attribute__((ext_vector_type(8))) short short8;
typedef __attribute__((ext_vector_type(4))) short short4_t;
typedef __attribute__((ext_vector_type(4))) float floatx4;

typedef __attribute__((address_space(1))) const unsigned int gu32;
typedef __attribute__((address_space(3))) unsigned int lu32;

__device__ __forceinline__ void g2lds16(const void* g, void* l) {
    // async global->LDS DMA, 16B per lane; LDS dest = wave-uniform base + lane*16
    __builtin_amdgcn_global_load_lds((gu32*)g, (lu32*)l, 16, 0, 0);
}

__device__ __forceinline__ short f2bf(float f) {
    union { float f; unsigned u; } v; v.f = f;
    unsigned r = (v.u + 0x7FFF + ((v.u >> 16) & 1)) >> 16;  // RNE
    return (short)r;
}

__device__ __forceinline__ unsigned pk2(float a, float b) {
    __hip_bfloat162 h = __float22bfloat162_rn(make_float2(a, b));
    return *(unsigned*)&h;   // low = a, high = b
}

__device__ __forceinline__ float ex2(float x) {
#if __has_builtin(__builtin_amdgcn_exp2f)
    return __builtin_amdgcn_exp2f(x);
#else
    return exp2f(x);
#endif
}

// ---------------------------------------------------------------------------
// K1: fp32 -> bf16 convert (X, Wq|Wk|Wv concat) + mask prescale by log2e
// ---------------------------------------------------------------------------
__global__ __launch_bounds__(256) void convert_kernel(
    const float4* __restrict__ X, const float4* __restrict__ Wq,
    const float4* __restrict__ Wk, const float4* __restrict__ Wv,
    const float4* __restrict__ Mask,
    short4_t* __restrict__ Xb, short4_t* __restrict__ Wb,
    float4* __restrict__ Mw)
{
    int idx = blockIdx.x * 256 + threadIdx.x;      // 1,836,032 total
    if (idx >= 1835008) {                           // mask: 1024 float4
        int t = idx - 1835008;
        float4 f = Mask[t];
        float4 o;
        o.x = f.x * LOG2E; o.y = f.y * LOG2E;
        o.z = f.z * LOG2E; o.w = f.w * LOG2E;
        Mw[t] = o;
        return;
    }
    const float4* src; short4_t* dst;
    if (idx < 1048576) { src = X + idx; dst = Xb + idx; }
    else {
        int t = idx - 1048576;
        int sel = t >> 18;                          // 262144 float4 per W
        int wi  = t & 0x3FFFF;
        src = (sel == 0 ? Wq : sel == 1 ? Wk : Wv) + wi;
        dst = Wb + (sel << 18) + wi;
    }
    float4 f = *src;
    short4_t o;
    o.x = f2bf(f.x); o.y = f2bf(f.y); o.z = f2bf(f.z); o.w = f2bf(f.w);
    *dst = o;
}

// ---------------------------------------------------------------------------
// K2: QKV projection, bf16 MFMA. C[4096][3072] = Xb[4096][1024] * Wb^T.
// 128x128 tile, BK=64, global_load_lds w=16, XOR-swizzled LDS.
// q -> [B,NH,S,HD] scaled by 0.125*log2e; k -> [B,NH,S,HD];
// v -> TRANSPOSED [B*NH, HD, S] with key order PERMUTED within each
//     64-column group: block-of-4 b=(kh,jh,q) -> kh*8+q*2+jh, so the
//     attention PV A-fragment (packed from the S^T C-layout without any
//     cross-lane moves) contracts against matching V columns.
// ---------------------------------------------------------------------------
__global__ __launch_bounds__(256, 3) void qkv_mfma_kernel(
    const short* __restrict__ Xb, const short* __restrict__ Wb,
    const float* __restrict__ bq, const float* __restrict__ bk,
    const float* __restrict__ bv,
    short* __restrict__ qo, short* __restrict__ ko, short* __restrict__ vT)
{
    __shared__ short Sm[128 * 132];      // A/B staging (16384) + V transpose (16896)
    short* As = Sm;
    short* Bs = Sm + 8192;

    const int tid  = threadIdx.x;
    const int lane = tid & 63;
    const int w    = tid >> 6;
    const int l    = lane & 15, quad = lane >> 4;
    const int gM   = blockIdx.y * 128;
    const int gN   = blockIdx.x * 128;      // 0..3071 across q|k|v
    const int wm   = (w >> 1) * 64, wn = (w & 1) * 64;
    const int ci   = lane >> 3, pb = lane & 7;

    floatx4 acc[4][4] = {};

    for (int kt = 0; kt < HSZ / 64; ++kt) {
        const int k0 = kt * 64;
        __syncthreads();
        #pragma unroll
        for (int u = 0; u < 4; ++u) {
            int c  = w * 4 + u;                 // chunk 0..15 (1KB each)
            int r  = c * 8 + ci;                // tile row
            int lb = pb ^ (r & 7);              // logical 16B block
            g2lds16(Xb + (size_t)(gM + r) * HSZ + k0 + lb * 8, &As[c * 512]);
            g2lds16(Wb + (size_t)(gN + r) * HSZ + k0 + lb * 8, &Bs[c * 512]);
        }
        __syncthreads();
        #pragma unroll
        for (int kk = 0; kk < 2; ++kk) {
            short8 a[4], b[4];
            #pragma unroll
            for (int i = 0; i < 4; ++i) {
                int m = wm + i * 16 + l;
                a[i] = *(const short8*)&As[m * 64 + (((quad + kk * 4) ^ (m & 7)) << 3)];
                int n = wn + i * 16 + l;
                b[i] = *(const short8*)&Bs[n * 64 + (((quad + kk * 4) ^ (n & 7)) << 3)];
            }
            #pragma unroll
            for (int i = 0; i < 4; ++i)
                #pragma unroll
                for (int j = 0; j < 4; ++j)
                    acc[i][j] = __builtin_amdgcn_mfma_f32_16x16x32_bf16(
                        a[i], b[j], acc[i][j], 0, 0, 0);
        }
    }

    const int mat = gN >> 10;                   // 0=q 1=k 2=v

    if (mat == 2) {
        // V: bias + LDS transpose, write [bh][d][s] with permuted key blocks
        __syncthreads();
        #pragma unroll
        for (int j = 0; j < 4; ++j) {
            int fl = wn + j * 16 + l;               // feature local 0..127
            float bv_ = bv[(gN & 1023) + fl];
            #pragma unroll
            for (int i = 0; i < 4; ++i)
                #pragma unroll
                for (int r = 0; r < 4; ++r)
                    Sm[fl * 132 + wm + i * 16 + quad * 4 + r]
                        = f2bf(acc[i][j][r] + bv_);
        }
        __syncthreads();
        const int bb = gM >> 11, ss0 = gM & (SEQ - 1);
        #pragma unroll
        for (int it = 0; it < 16; ++it) {
            int f = (tid >> 5) + it * 8;
            int c = (tid & 31) * 4;
            short4_t val = *(const short4_t*)&Sm[f * 132 + c];
            int b = (c >> 2) & 15;                  // logical block-of-4
            int cp = (c & ~63) | ((((b & 8) | ((b & 3) << 1) | ((b >> 2) & 1))) << 2);
            int nft = (gN & 1023) + f;
            int head = nft >> 6, d = nft & 63;
            *(short4_t*)&vT[(((size_t)(bb * NHEAD + head)) * HDIM + d) * SEQ
                            + ss0 + cp] = val;
        }
        return;
    }

    const float* bias = (mat == 0) ? bq : bk;
    short* dst        = (mat == 0) ? qo : ko;
    const float qscale = (mat == 0) ? 0.125f * LOG2E : 1.0f;

    #pragma unroll
    for (int j = 0; j < 4; ++j) {
        int nft = (gN & 1023) + wn + j * 16 + l;   // feature 0..1023
        float bv_ = bias[nft];
        int head = nft >> 6, d = nft & 63;
        #pragma unroll
        for (int i = 0; i < 4; ++i) {
            #pragma unroll
            for (int r = 0; r < 4; ++r) {
                int gr = gM + wm + i * 16 + quad * 4 + r;    // C row = quad*4+reg
                int bb = gr >> 11, ss = gr & (SEQ - 1);
                float val = (acc[i][j][r] + bv_) * qscale;
                dst[((((size_t)bb * NHEAD + head) * SEQ + ss) << 6) + d] = f2bf(val);
            }
        }
    }
}

// ---------------------------------------------------------------------------
// K3: MFMA flash attention. Block = 4 waves, Q-tile 128.
//   Wave (qh=w&1, kh=w>>1): 64 queries (qh half) x 32 keys (kh half of each
//   64-key tile). S^T = K Q^T (A=K, B=Q): C col=lane&15=query, row=key.
//   No-max exp2 softmax; mask enters as accumulator init; l kept as
//   lane-partial sums, reduced once at the end.
//
//   NEW (this round): S-tile double pipeline (T15). Two S register buffers
//   (sA/sB) with statically-named 2-phase loop (rule #20: no runtime reg
//   indexing). Each phase: prefetch(t+2) -> QK^T(t+1) [independent MFMA]
//   -> softmax(t) [independent VALU] -> PV(t), so the compiler can hide the
//   exp2/pack chain under the next tile's QK^T instead of relying purely on
//   cross-wave overlap (MfmaUtil was 25%, VALUBusy 41%, both unsaturated).
//   Barrier count per tile unchanged; prefetch->use distance unchanged.
//   s_setprio(1) wraps MFMA clusters (T5).
// ---------------------------------------------------------------------------
__global__ __launch_bounds__(256, 2) void attn_kernel(
    const short* __restrict__ Qg, const short* __restrict__ Kg,
    const short* __restrict__ VTg, const float* __restrict__ maskw,
    float* __restrict__ out)
{
    __shared__ short Qs[128 * 64];
    __shared__ alignas(16) short Ks[2][64 * 64];   // reused as fp32 combine buf
    __shared__ alignas(16) short Vt[2][64 * 64];   // reused as fp32 combine buf
    __shared__ alignas(16) float Ms[2][64];
    __shared__ alignas(16) float Lx[2][4][64];

    const int tid  = threadIdx.x;
    const int lane = tid & 63;
    const int w    = tid >> 6;
    const int l    = lane & 15, quad = lane >> 4;
    const int idx  = blockIdx.x;
    const int bh   = idx & 31;              // bh%8 == XCD -> K/V stays in one L2
    const int qt   = idx >> 5;              // 16 Q-tiles of 128
    const int batch = bh >> 4, head = bh & 15;
    const int qh = w & 1, kh = w >> 1;
    const int ci = lane >> 3, pb = lane & 7;

    const short* Qb = Qg + ((size_t)bh * SEQ + qt * 128) * HDIM;
    const short* Kb = Kg + (size_t)bh * SEQ * HDIM;
    const short* Vb = VTg + (size_t)bh * HDIM * SEQ;
    const float* mrow = maskw + (size_t)batch * SEQ;   // pre-scaled by log2e

    // initial staging: Q tile (16 chunks), K tiles 0+1, V tile 0, masks 0+1
    #pragma unroll
    for (int u = 0; u < 4; ++u) {
        int c = w * 4 + u;
        int r = c * 8 + ci;
        int lb = pb ^ (r & 7);
        g2lds16(Qb + (size_t)r * HDIM + lb * 8, &Qs[c * 512]);
    }
    #pragma unroll
    for (int u = 0; u < 2; ++u) {
        int c = w * 2 + u;
        int r = c * 8 + ci;
        int lb = pb ^ (r & 7);
        g2lds16(Kb + (size_t)r * HDIM + lb * 8, &Ks[0][c * 512]);
        g2lds16(Kb + (size_t)(64 + r) * HDIM + lb * 8, &Ks[1][c * 512]);
        g2lds16(Vb + (size_t)r * SEQ + lb * 8, &Vt[0][c * 512]);
    }
    if (tid < 16) g2lds16(mrow + tid * 4, &Ms[0][0]);
    if (tid >= 64 && tid < 80) g2lds16(mrow + 64 + (tid - 64) * 4, &Ms[1][0]);
    __syncthreads();

    // hoist Q B-fragments: B[k=d][n=query], queries qh*64 + n*16 + l
    short8 aq[4][2];
    #pragma unroll
    for (int n = 0; n < 4; ++n)
        #pragma unroll
        for (int kk = 0; kk < 2; ++kk) {
            int m = qh * 64 + n * 16 + l;
            aq[n][kk] = *(const short8*)&Qs[m * 64 + (((quad + kk * 4) ^ (m & 7)) << 3)];
        }

    floatx4 o[4][4] = {};
    float l_i[4] = {0.f, 0.f, 0.f, 0.f};
    floatx4 sA[2][4], sB[2][4];

    // ---- phase helpers (all-static unroll inside; inlined) ----
    auto PRE = [&](int tK, short* Kdst, float* Mdst, int tV, short* Vdst) {
        if (tK < SEQ / 64) {                 // prefetch K(tK)+mask(tK)
            const int r0 = tK * 64;
            #pragma unroll
            for (int u = 0; u < 2; ++u) {
                int c = w * 2 + u;
                int r = c * 8 + ci;
                int lb = pb ^ (r & 7);
                g2lds16(Kb + (size_t)(r0 + r) * HDIM + lb * 8, Kdst + c * 512);
            }
            if (tid < 16) g2lds16(mrow + r0 + tid * 4, Mdst);
        }
        if (tV < SEQ / 64) {                 // prefetch V(tV)
            const int c0 = tV * 64;
            #pragma unroll
            for (int u = 0; u < 2; ++u) {
                int c = w * 2 + u;
                int r = c * 8 + ci;
                int lb = pb ^ (r & 7);
                g2lds16(Vb + (size_t)r * SEQ + c0 + lb * 8, Vdst + c * 512);
            }
        }
    };

    auto QKT = [&](floatx4 (&s)[2][4], const short* Kbuf, const float* Mbuf) {
        float4 mq[2];
        #pragma unroll
        for (int m = 0; m < 2; ++m)
            mq[m] = *(const float4*)&Mbuf[kh * 32 + m * 16 + quad * 4];
        #pragma unroll
        for (int m = 0; m < 2; ++m) {
            floatx4 ini = {mq[m].x, mq[m].y, mq[m].z, mq[m].w};
            #pragma unroll
            for (int n = 0; n < 4; ++n) s[m][n] = ini;
        }
        #pragma unroll
        for (int kk = 0; kk < 2; ++kk) {
            short8 ak[2];
            #pragma unroll
            for (int m = 0; m < 2; ++m) {
                int kr = kh * 32 + m * 16 + l;
                ak[m] = *(const short8*)&Kbuf[kr * 64 + (((quad + kk * 4) ^ (kr & 7)) << 3)];
            }
            __builtin_amdgcn_s_setprio(1);
            #pragma unroll
            for (int m = 0; m < 2; ++m)
                #pragma unroll
                for (int n = 0; n < 4; ++n)
                    s[m][n] = __builtin_amdgcn_mfma_f32_16x16x32_bf16(
                        ak[m], aq[n][kk], s[m][n], 0, 0, 0);
            __builtin_amdgcn_s_setprio(0);
        }
    };

    auto SMPV = [&](floatx4 (&s)[2][4], const short* Vbuf) {
        short8 bvf[4];                       // issue LDS reads first (hide lgkm)
        #pragma unroll
        for (int nd = 0; nd < 4; ++nd) {
            int d = nd * 16 + l;
            bvf[nd] = *(const short8*)&Vbuf[d * 64 + (((kh * 4 + quad) ^ (d & 7)) << 3)];
        }
        // P = exp2(s); l partial per lane (cross-quad reduce deferred to end)
        #pragma unroll
        for (int n = 0; n < 4; ++n) {
            float rs = 0.f;
            #pragma unroll
            for (int m = 0; m < 2; ++m) {
                s[m][n][0] = ex2(s[m][n][0]);
                s[m][n][1] = ex2(s[m][n][1]);
                s[m][n][2] = ex2(s[m][n][2]);
                s[m][n][3] = ex2(s[m][n][3]);
                rs += (s[m][n][0] + s[m][n][1]) + (s[m][n][2] + s[m][n][3]);
            }
            l_i[n] += rs;
        }
        // pack P into PV A-fragments: pure local regs (V columns permuted)
        short8 ap[4];
        #pragma unroll
        for (int n = 0; n < 4; ++n) {
            union { unsigned u[4]; short8 s8; } pu;
            pu.u[0] = pk2(s[0][n][0], s[0][n][1]);
            pu.u[1] = pk2(s[0][n][2], s[0][n][3]);
            pu.u[2] = pk2(s[1][n][0], s[1][n][1]);
            pu.u[3] = pk2(s[1][n][2], s[1][n][3]);
            ap[n] = pu.s8;
        }
        __builtin_amdgcn_s_setprio(1);
        #pragma unroll
        for (int nq = 0; nq < 4; ++nq)
            #pragma unroll
            for (int nd = 0; nd < 4; ++nd)
                o[nq][nd] = __builtin_amdgcn_mfma_f32_16x16x32_bf16(
                    ap[nq], bvf[nd], o[nq][nd], 0, 0, 0);
        __builtin_amdgcn_s_setprio(0);
    };

    // prologue compute: sA = S(0) from Ks[0]/Ms[0]
    QKT(sA, &Ks[0][0], &Ms[0][0]);
    __syncthreads();   // Ks[0]/Ms[0] reads done before loop's first prefetch

    for (int kt = 0; kt < SEQ / 64; kt += 2) {
        // phase A: tile kt. sA=S(kt) ready; V(kt) in Vt[0]; K(kt+1) in Ks[1].
        PRE(kt + 2, &Ks[0][0], &Ms[0][0], kt + 1, &Vt[1][0]);
        QKT(sB, &Ks[1][0], &Ms[1][0]);       // S(kt+1): independent MFMA
        SMPV(sA, &Vt[0][0]);                 // softmax+PV tile kt
        __syncthreads();
        // phase B: tile kt+1. sB=S(kt+1); V(kt+1) in Vt[1]; K(kt+2) in Ks[0].
        PRE(kt + 3, &Ks[1][0], &Ms[1][0], kt + 2, &Vt[0][0]);
        if (kt + 2 < SEQ / 64)
            QKT(sA, &Ks[0][0], &Ms[0][0]);   // S(kt+2)
        SMPV(sB, &Vt[1][0]);                 // softmax+PV tile kt+1
        __syncthreads();
    }

    // ---- wave-pair combine (kh=1 partials -> kh=0 waves) ----
    float* reg = (qh == 0) ? (float*)&Ks[0][0] : (float*)&Vt[0][0];
    if (kh == 1) {
        #pragma unroll
        for (int nq = 0; nq < 4; ++nq)
            #pragma unroll
            for (int nd = 0; nd < 4; ++nd)
                *(floatx4*)&reg[((nq * 4 + nd) * 64 + lane) * 4] = o[nq][nd];
        #pragma unroll
        for (int n = 0; n < 4; ++n) Lx[qh][n][lane] = l_i[n];
    }
    __syncthreads();
    if (kh == 0) {
        #pragma unroll
        for (int nq = 0; nq < 4; ++nq)
            #pragma unroll
            for (int nd = 0; nd < 4; ++nd)
                o[nq][nd] += *(const floatx4*)&reg[((nq * 4 + nd) * 64 + lane) * 4];
        #pragma unroll
        for (int n = 0; n < 4; ++n) {
            float t = l_i[n] + Lx[qh][n][lane];
            t += __shfl_xor(t, 16);
            t += __shfl_xor(t, 32);
            l_i[n] = t;
        }
        // epilogue: out[b][s][h*64+d] fp32; query = nq*16+quad*4+r, d = nd*16+l
        #pragma unroll
        for (int nq = 0; nq < 4; ++nq) {
            #pragma unroll
            for (int r = 0; r < 4; ++r) {
                float inv = 1.0f / __shfl(l_i[nq], (lane & 48) + quad * 4 + r);
                int qrow = qt * 128 + qh * 64 + nq * 16 + quad * 4 + r;
                #pragma unroll
                for (int nd = 0; nd < 4; ++nd)
                    out[((size_t)batch * SEQ + qrow) * HSZ + head * HDIM + nd * 16 + l]
                        = o[nq][nd][r] * inv;
            }
        }
    }
}

extern "C" void kernel_launch(void* const* d_in, const int* in_sizes, int n_in,
                              void* d_out, int out_size, void* d_ws, size_t ws_size,
                              hipStream_t stream) {
    const float* hs   = (const float*)d_in[0];
    const float* mask = (const float*)d_in[1];
    const float* Wq   = (const float*)d_in[2];
    const float* bq   = (const float*)d_in[3];
    const float* Wk   = (const float*)d_in[4];
    const float* bk   = (const float*)d_in[5];
    const float* Wv   = (const float*)d_in[6];
    const float* bv   = (const float*)d_in[7];
    float* out = (float*)d_out;

    // workspace (shorts): Xb 4.19M | Wb 3.15M | qb | kb | vT 4.19M each | Mw
    short* Xb = (short*)d_ws;
    short* Wb = Xb + 4194304;
    short* qb = Wb + 3145728;
    short* kb = qb + 4194304;
    short* vT = kb + 4194304;
    float* Mw = (float*)(vT + 4194304);   // 4096 floats

    convert_kernel<<<7172, 256, 0, stream>>>(
        (const float4*)hs, (const float4*)Wq, (const float4*)Wk, (const float4*)Wv,
        (const float4*)mask, (short4_t*)Xb, (short4_t*)Wb, (float4*)Mw);

    dim3 g2(3 * HSZ / 128, BATCH * SEQ / 128);   // 24 x 32
    qkv_mfma_kernel<<<g2, 256, 0, stream>>>(Xb, Wb, bq, bk, bv, qb, kb, vT);

    attn_kernel<<<512, 256, 0, stream>>>(qb, kb, vT, Mw, out);
}